// Round 12
// baseline (139.432 us; speedup 1.0000x reference)
//
#include <hip/hip_runtime.h>

#define NUM_E 1024
#define DIM 64
#define NROWS 65536                  // 64*32*32
#define OUT0_SIZE 4194304            // 64*64*32*32
#define OUT1_OFF OUT0_SIZE
#define LOSS_OFF (OUT0_SIZE + 65536) // 4259840

// ---- MFMA-path constants ----
// MARGIN covers 2*ERR, ERR = bf16-input rounding (<=5.6e-4 at |z|_1<=75)
// + dropped-En (<=6.1e-5) + fp32 accum slop (~1e-5) => 2*ERR ~= 1.3e-3.
// MARGIN 2.5e-3 = 1.9x that bound (validated R3-R11: passed, absmax equal
// to the exact kernel's). Expected candidates/row ~1.7; CAP 23 =>
// P(overflow) ~1e-15/row; overflow falls back to the exact full scan.
//
// SESSION CONVERGENCE (R11): scan structure = R4 (best of 11 variants,
// 69us kernel). R12 delta: SINGLE-DISPATCH — prep2 eliminated. Each block
// packs its own eB LDS slice from e (identical f2bf(-2e) math + layout),
// computes En inline in the rescore (same np-pairwise order from the same
// e-row loads => bit-identical s), runs the MFMA-layout self-test itself
// (wave 0 -> LDS flag). Loss slot zeroed by a 4-byte hipMemsetAsync.
// Falsified alternatives (do not revisit): 16-wave blocks (allocator
// targets 8 waves/EU -> z spills: R5/R6/R9), 16-rows/wave (2x load:MFMA
// ratio + write amplification: R9/R10), ballot collection (R7, 520us),
// reg prefetch (neutral: R8), waves_per_eu pinning (worse: R6).
#define MARGIN 2.5e-3f
#define CAND_CAP 23

typedef float f32x4_t __attribute__((ext_vector_type(4)));
typedef short s16x8  __attribute__((ext_vector_type(8)));

// RNE float->bf16 (no NaN inputs here)
__device__ __forceinline__ unsigned short f2bf(float x) {
    unsigned u = __float_as_uint(x);
    u += 0x7FFFu + ((u >> 16) & 1u);
    return (unsigned short)(u >> 16);
}

__device__ __forceinline__ s16x8 pack_bf8(float4 a, float4 b) {
    s16x8 v;
    v[0] = (short)f2bf(a.x); v[1] = (short)f2bf(a.y);
    v[2] = (short)f2bf(a.z); v[3] = (short)f2bf(a.w);
    v[4] = (short)f2bf(b.x); v[5] = (short)f2bf(b.y);
    v[6] = (short)f2bf(b.z); v[7] = (short)f2bf(b.w);
    return v;
}

#define SQ8(A, B)                                              \
    { float p;                                                 \
      p = A.x*A.x; r0 = r0 + p;  p = A.y*A.y; r1 = r1 + p;     \
      p = A.z*A.z; r2 = r2 + p;  p = A.w*A.w; r3 = r3 + p;     \
      p = B.x*B.x; r4 = r4 + p;  p = B.y*B.y; r5 = r5 + p;     \
      p = B.z*B.z; r6 = r6 + p;  p = B.w*B.w; r7 = r7 + p; }

#define EPI4(Q, ZQ)                                            \
    { float4 evv = erp[Q]; float df;                           \
      o0[(size_t)(4*Q+0)*1024] = evv.x; df = evv.x - ZQ.x; lsum = fmaf(df,df,lsum); \
      o0[(size_t)(4*Q+1)*1024] = evv.y; df = evv.y - ZQ.y; lsum = fmaf(df,df,lsum); \
      o0[(size_t)(4*Q+2)*1024] = evv.z; df = evv.z - ZQ.z; lsum = fmaf(df,df,lsum); \
      o0[(size_t)(4*Q+3)*1024] = evv.w; df = evv.w - ZQ.w; lsum = fmaf(df,df,lsum); }

// one 8-element group of the fused rescore: e*e partials in np pairwise
// order (contract(off) scope) + ascending-d fmaf dot chain (fmaf exact).
#define RSG(G, ZA, ZB)                                         \
    { const float4 ai = ep[2*(G)], bi = ep[2*(G)+1];           \
      SQ8(ai, bi)                                              \
      m = fmaf(ai.x, ZA.x, m); m = fmaf(ai.y, ZA.y, m);        \
      m = fmaf(ai.z, ZA.z, m); m = fmaf(ai.w, ZA.w, m);        \
      m = fmaf(bi.x, ZB.x, m); m = fmaf(bi.y, ZB.y, m);        \
      m = fmaf(bi.z, ZB.z, m); m = fmaf(bi.w, ZB.w, m); }

// exact fp32 rescore with En computed INLINE from the same e-row loads:
// En_k = np_sumsq64(e_k) (identical pairwise order -> identical bits to
// the prep-computed En of R3-R11), m = sequential fmaf dot (identical to
// the validated DOT4 chain), s = (A - 2m) + En_k (validated grid).
__device__ __forceinline__ float vq_rescore_self(const int k,
        const float* __restrict__ e, const float A,
        const float4 z0, const float4 z1, const float4 z2, const float4 z3,
        const float4 z4, const float4 z5, const float4 z6, const float4 z7,
        const float4 z8, const float4 z9, const float4 z10, const float4 z11,
        const float4 z12, const float4 z13, const float4 z14, const float4 z15) {
#pragma clang fp contract(off)
    const float4* ep = (const float4*)(e + (size_t)k * DIM);
    float m = 0.0f;
    float r0,r1,r2,r3,r4,r5,r6,r7;
    {   // group 0: init partials (np order: r[j] = x[j]*x[j])
        const float4 a0 = ep[0], b0 = ep[1];
        float p;
        p = a0.x*a0.x; r0 = p;  p = a0.y*a0.y; r1 = p;
        p = a0.z*a0.z; r2 = p;  p = a0.w*a0.w; r3 = p;
        p = b0.x*b0.x; r4 = p;  p = b0.y*b0.y; r5 = p;
        p = b0.z*b0.z; r6 = p;  p = b0.w*b0.w; r7 = p;
        m = fmaf(a0.x, z0.x, m); m = fmaf(a0.y, z0.y, m);
        m = fmaf(a0.z, z0.z, m); m = fmaf(a0.w, z0.w, m);
        m = fmaf(b0.x, z1.x, m); m = fmaf(b0.y, z1.y, m);
        m = fmaf(b0.z, z1.z, m); m = fmaf(b0.w, z1.w, m);
    }
    RSG(1, z2,  z3)  RSG(2, z4,  z5)  RSG(3, z6,  z7)
    RSG(4, z8,  z9)  RSG(5, z10, z11) RSG(6, z12, z13) RSG(7, z14, z15)
    const float En_k = ((r0 + r1) + (r2 + r3)) + ((r4 + r5) + (r6 + r7));
    const float twoM = 2.0f * m;
    const float t = A - twoM;
    return t + En_k;
}

// SINGLE self-sufficient kernel: 512 thr = 8 waves x 32 rows = 256
// rows/block; grid 256 (1 block/CU). Per block: (1) pack -2*bf16(e) into
// the 128KB LDS codebook in MFMA B-frag order (same layout/values as the
// old prep2 path: seg = u*2+f, code = u*16+(lane&15), d0 = f*32+
// (lane>>4)*8); (2) MFMA-layout self-test (wave 0 -> LDS flag; bad =>
// exact full-scan path, slow but correct); (3) two-phase margin scan
// (verbatim R4); (4) exact rescore + outputs (verbatim R4 epilogue, En
// inline).
__global__ __launch_bounds__(512, 2)
void vq_mfma_kernel(const float* __restrict__ z,
                    const float* __restrict__ e,
                    float* __restrict__ out) {
    __shared__ unsigned short lds_e[65536];           // 128 KB, frag order
    __shared__ unsigned short candk[256][CAND_CAP];   // 11.5 KB (u16 codes)
    __shared__ int candcnt[256];                      // 1 KB
    __shared__ int flg_lds;

    const int tid  = threadIdx.x;
    const int lane = tid & 63;
    const int w    = __builtin_amdgcn_readfirstlane(tid >> 6);  // 0..7
    const int cc   = lane & 15;   // B-col (code within group) / A-row
    const int hh   = lane >> 4;   // k-subgroup / D-row-group
    const int n0   = blockIdx.x * 256;

    // ---- pack eB slice w (16 segs x 1KB) into LDS from e directly ----
#pragma unroll
    for (int i = 0; i < 16; ++i) {
        const int seg  = w * 16 + i;                  // 0..127
        const int u    = seg >> 1, f = seg & 1;
        const int code = u * 16 + (lane & 15);
        const int d0   = f * 32 + ((lane >> 4) << 3);
        const float4* sp = (const float4*)(e + (size_t)code * DIM + d0);
        float4 a = sp[0], b = sp[1];
        a.x *= -2.f; a.y *= -2.f; a.z *= -2.f; a.w *= -2.f;
        b.x *= -2.f; b.y *= -2.f; b.z *= -2.f; b.w *= -2.f;
        *(s16x8*)(lds_e + seg * 512 + lane * 8) = pack_bf8(a, b);
    }

    if (tid < 256) candcnt[tid] = 0;

    // ---- MFMA layout self-test (wave 0, asymmetric probe) ----
    if (tid < 64) {
        const int tcc = lane & 15, thh = lane >> 4;
        s16x8 ta, tb;
#pragma unroll
        for (int j = 0; j < 8; ++j) {
            const int k2 = thh * 8 + j;
            ta[j] = (short)((tcc == 0) ? f2bf((float)(k2 + 1)) : 0);
            tb[j] = (short)((tcc == 0) ? f2bf((float)(2 * k2 + 1))
                          : (tcc == 3 && k2 == 2) ? f2bf(1.0f) : 0);
        }
        f32x4_t td = {0.f, 0.f, 0.f, 0.f};
        td = __builtin_amdgcn_mfma_f32_16x16x32_bf16(ta, tb, td, 0, 0, 0);
        int ok = 1;
#pragma unroll
        for (int j = 0; j < 4; ++j) {
            const int row = thh * 4 + j;
            const float expv = (tcc == 0) ? (row == 0 ? 22352.0f : 0.0f)
                             : (tcc == 3) ? (row == 0 ? 3.0f : 0.0f) : 0.0f;
            ok = ok && (td[j] == expv);
        }
        const unsigned long long bal = __ballot(ok);
        if (lane == 0) flg_lds = (bal == 0xFFFFFFFFFFFFFFFFULL) ? 0 : 1;
    }

    // z fragments (bf16): rows w*32+cc (set A) and +16 (set B), K halves 0/1
    s16x8 az0, az1, az2, az3;
    {
        const float* zr0 = z + (size_t)(n0 + w * 32 + cc) * DIM + hh * 8;
        const float* zr1 = zr0 + (size_t)16 * DIM;
        az0 = pack_bf8(*(const float4*)(zr0),      *(const float4*)(zr0 + 4));
        az1 = pack_bf8(*(const float4*)(zr0 + 32), *(const float4*)(zr0 + 36));
        az2 = pack_bf8(*(const float4*)(zr1),      *(const float4*)(zr1 + 4));
        az3 = pack_bf8(*(const float4*)(zr1 + 32), *(const float4*)(zr1 + 36));
    }

    __syncthreads();   // packing ds_writes + candcnt init + flag complete
    const int bad = flg_lds;

    if (!bad) {
        const s16x8* lp = (const s16x8*)lds_e;        // [u*128 + f*64 + lane]

        // ---------------- phase 1: min scan (LDS, no barriers) ------------
        float b1v[8];
#pragma unroll
        for (int j = 0; j < 8; ++j) b1v[j] = 3.4e38f;

#pragma unroll 8
        for (int u = 0; u < 64; ++u) {
            const s16x8 eb0 = lp[u * 128 + lane];
            const s16x8 eb1 = lp[u * 128 + 64 + lane];
            f32x4_t accA = {0.f, 0.f, 0.f, 0.f};
            f32x4_t accB = {0.f, 0.f, 0.f, 0.f};
            accA = __builtin_amdgcn_mfma_f32_16x16x32_bf16(az0, eb0, accA, 0, 0, 0);
            accA = __builtin_amdgcn_mfma_f32_16x16x32_bf16(az1, eb1, accA, 0, 0, 0);
            accB = __builtin_amdgcn_mfma_f32_16x16x32_bf16(az2, eb0, accB, 0, 0, 0);
            accB = __builtin_amdgcn_mfma_f32_16x16x32_bf16(az3, eb1, accB, 0, 0, 0);
#pragma unroll
            for (int j = 0; j < 4; ++j) {
                b1v[j]     = fminf(b1v[j],     accA[j]);
                b1v[j + 4] = fminf(b1v[j + 4], accB[j]);
            }
        }

        // per-row bf16 min across the 16 cc-classes -> threshold
        float th[8];
#pragma unroll
        for (int j = 0; j < 8; ++j) {
            float mv = b1v[j];
            mv = fminf(mv, __shfl_xor(mv, 1));
            mv = fminf(mv, __shfl_xor(mv, 2));
            mv = fminf(mv, __shfl_xor(mv, 4));
            mv = fminf(mv, __shfl_xor(mv, 8));
            th[j] = mv + MARGIN;
        }

        // ---------------- phase 2: candidate collection (LDS) -------------
#pragma unroll 4
        for (int u = 0; u < 64; ++u) {
            const s16x8 eb0 = lp[u * 128 + lane];
            const s16x8 eb1 = lp[u * 128 + 64 + lane];
            f32x4_t accA = {0.f, 0.f, 0.f, 0.f};
            f32x4_t accB = {0.f, 0.f, 0.f, 0.f};
            accA = __builtin_amdgcn_mfma_f32_16x16x32_bf16(az0, eb0, accA, 0, 0, 0);
            accA = __builtin_amdgcn_mfma_f32_16x16x32_bf16(az1, eb1, accA, 0, 0, 0);
            accB = __builtin_amdgcn_mfma_f32_16x16x32_bf16(az2, eb0, accB, 0, 0, 0);
            accB = __builtin_amdgcn_mfma_f32_16x16x32_bf16(az3, eb1, accB, 0, 0, 0);
            float worst = accA[0] - th[0];
            worst = fminf(worst, accA[1] - th[1]);
            worst = fminf(worst, accA[2] - th[2]);
            worst = fminf(worst, accA[3] - th[3]);
            worst = fminf(worst, accB[0] - th[4]);
            worst = fminf(worst, accB[1] - th[5]);
            worst = fminf(worst, accB[2] - th[6]);
            worst = fminf(worst, accB[3] - th[7]);
            if (__any(worst <= 0.0f)) {
                const int kc = u * 16 + cc;
#pragma unroll
                for (int j = 0; j < 4; ++j) {
                    if (accA[j] <= th[j]) {
                        const int rr = w * 32 + hh * 4 + j;
                        const int slot = atomicAdd(&candcnt[rr], 1);
                        if (slot < CAND_CAP) candk[rr][slot] = (unsigned short)kc;
                    }
                    if (accB[j] <= th[j + 4]) {
                        const int rr = w * 32 + 16 + hh * 4 + j;
                        const int slot = atomicAdd(&candcnt[rr], 1);
                        if (slot < CAND_CAP) candk[rr][slot] = (unsigned short)kc;
                    }
                }
            }
        }
    }

    // -------- epilogue: exact rescore + outputs (wave w, its 32 rows) -----
    if (lane < 32) {
        const int r = w * 32 + lane;
        const int n = n0 + r;
        float4 z0,z1,z2,z3,z4,z5,z6,z7,z8,z9,z10,z11,z12,z13,z14,z15;
        {
            const float4* zp = (const float4*)(z + (size_t)n * DIM);
            z0=zp[0]; z1=zp[1]; z2=zp[2]; z3=zp[3]; z4=zp[4]; z5=zp[5]; z6=zp[6]; z7=zp[7];
            z8=zp[8]; z9=zp[9]; z10=zp[10]; z11=zp[11]; z12=zp[12]; z13=zp[13]; z14=zp[14]; z15=zp[15];
        }
        float A;
        {
#pragma clang fp contract(off)
            float r0,r1,r2,r3,r4,r5,r6,r7;
            { float p;
              p = z0.x*z0.x; r0 = p;  p = z0.y*z0.y; r1 = p;
              p = z0.z*z0.z; r2 = p;  p = z0.w*z0.w; r3 = p;
              p = z1.x*z1.x; r4 = p;  p = z1.y*z1.y; r5 = p;
              p = z1.z*z1.z; r6 = p;  p = z1.w*z1.w; r7 = p; }
            SQ8(z2,  z3)  SQ8(z4,  z5)  SQ8(z6,  z7)
            SQ8(z8,  z9)  SQ8(z10, z11) SQ8(z12, z13) SQ8(z14, z15)
            A = ((r0 + r1) + (r2 + r3)) + ((r4 + r5) + (r6 + r7));
        }
#define RS(K) vq_rescore_self((K), e, A, z0,z1,z2,z3,z4,z5,z6,z7,z8,z9,z10,z11,z12,z13,z14,z15)
        const int cnt = bad ? 0 : candcnt[r];
        float best = 3.4e38f;
        int bk = 0x7FFFFFFF;
        if (cnt >= 1 && cnt <= CAND_CAP) {
            for (int i = 0; i < cnt; ++i) {
                const int k = candk[r][i];
                const float s = RS(k);
                if (s < best || (s == best && k < bk)) { best = s; bk = k; }
            }
        }
        if ((unsigned)bk > 1023u) {   // bad-layout flag / overflow: exact full scan
            best = 3.4e38f; bk = 0;
            for (int k = 0; k < NUM_E; ++k) {
                const float s = RS(k);
                if (s < best) { best = s; bk = k; }
            }
        }
#undef RS
        const int b  = n >> 10;
        const int hw = n & 1023;
        const float4* erp = (const float4*)(e + (size_t)bk * DIM);
        float* o0 = out + (size_t)b * 65536 + hw;
        float lsum = 0.0f;
        EPI4(0,  z0)  EPI4(1,  z1)  EPI4(2,  z2)  EPI4(3,  z3)
        EPI4(4,  z4)  EPI4(5,  z5)  EPI4(6,  z6)  EPI4(7,  z7)
        EPI4(8,  z8)  EPI4(9,  z9)  EPI4(10, z10) EPI4(11, z11)
        EPI4(12, z12) EPI4(13, z13) EPI4(14, z14) EPI4(15, z15)
        out[OUT1_OFF + n] = (float)bk;
#pragma unroll
        for (int off = 16; off > 0; off >>= 1)
            lsum += __shfl_down(lsum, off, 32);
        if (lane == 0)
            atomicAdd(&out[LOSS_OFF], lsum * (1.25f / 4194304.0f));
    }
}

extern "C" void kernel_launch(void* const* d_in, const int* in_sizes, int n_in,
                              void* d_out, int out_size, void* d_ws, size_t ws_size,
                              hipStream_t stream) {
    const float* z = (const float*)d_in[0];       // [65536, 64] fp32
    const float* e = (const float*)d_in[1];       // [1024, 64] fp32
    float* out = (float*)d_out;

    // zero the loss accumulator (d_out is re-poisoned every call);
    // hipMemsetAsync is stream-ordered + graph-capturable.
    hipMemsetAsync((char*)d_out + (size_t)LOSS_OFF * 4, 0, 4, stream);
    vq_mfma_kernel<<<NROWS / 256, 512, 0, stream>>>(z, e, out);
}